// Round 4
// baseline (228.145 us; speedup 1.0000x reference)
//
#include <hip/hip_runtime.h>
#include <hip/hip_bf16.h>
#include <math.h>

#define N_TOK 8192
#define DIM 1024
#define NEXP 16
#define CAP 1280
#define FDIM 512
#define NROUTE (N_TOK * 2)
#define NCHUNK 64
#define ECAP (NEXP * CAP)        /* 20480 */
#define TOTROW (ECAP + N_TOK)    /* 28672 */

typedef __hip_bfloat16 bf16;
typedef unsigned short ushort_t;
typedef __attribute__((ext_vector_type(8))) short bf16x8;
typedef __attribute__((ext_vector_type(4))) float f32x4;

__device__ __forceinline__ float gelu_exact(float x) {
    return 0.5f * x * (1.0f + erff(x * 0.70710678118654752f));
}

__device__ __forceinline__ float bf2f(unsigned short u) {
    union { float f; unsigned int i; } v; v.i = ((unsigned int)u) << 16; return v.f;
}

__device__ __forceinline__ unsigned short f2b(float f) {
    union { __hip_bfloat16 h; unsigned short u; } v;
    v.h = __float2bfloat16(f);
    return v.u;
}

__device__ __forceinline__ void gload16(const void* g, void* l) {
    __builtin_amdgcn_global_load_lds(
        (const __attribute__((address_space(1))) unsigned int*)g,
        (__attribute__((address_space(3))) unsigned int*)l,
        16, 0, 0);
}

// ---------------- convert x fp32 -> bf16 ----------------
__global__ __launch_bounds__(256) void convert_x_kernel(
    const float* __restrict__ x, ushort_t* __restrict__ x_bf)
{
    int i = (blockIdx.x * 256 + threadIdx.x) * 8;
    float4 a = *reinterpret_cast<const float4*>(x + i);
    float4 b = *reinterpret_cast<const float4*>(x + i + 4);
    bf16x8 o;
    o[0] = (short)f2b(a.x); o[1] = (short)f2b(a.y);
    o[2] = (short)f2b(a.z); o[3] = (short)f2b(a.w);
    o[4] = (short)f2b(b.x); o[5] = (short)f2b(b.y);
    o[6] = (short)f2b(b.z); o[7] = (short)f2b(b.w);
    *reinterpret_cast<bf16x8*>(x_bf + i) = o;
}

// ---------------- transpose+convert weights: fp32 [K][N] -> bf16 [N][K] ----------------
__global__ __launch_bounds__(256) void transpose_w_kernel(
    const float* __restrict__ w1, const float* __restrict__ w2,
    const float* __restrict__ sw1, const float* __restrict__ sw2,
    ushort_t* __restrict__ w1t, ushort_t* __restrict__ w2t,
    ushort_t* __restrict__ sw1t, ushort_t* __restrict__ sw2t)
{
    __shared__ float tileT[64][65];   // [n][k]
    int bx = blockIdx.x;
    const float* src; ushort_t* dst; int K, N, kt, nt;
    if (bx < 2048) {                      // w1: per-expert [1024][512]
        int e = bx >> 7, r = bx & 127;
        K = 1024; N = 512; kt = r >> 3; nt = r & 7;
        src = w1 + (size_t)e * K * N; dst = w1t + (size_t)e * K * N;
    } else if (bx < 4096) {               // w2: per-expert [512][1024]
        int b2 = bx - 2048, e = b2 >> 7, r = b2 & 127;
        K = 512; N = 1024; kt = r >> 4; nt = r & 15;
        src = w2 + (size_t)e * K * N; dst = w2t + (size_t)e * K * N;
    } else if (bx < 4224) {               // sw1 [1024][512]
        int r = bx - 4096;
        K = 1024; N = 512; kt = r >> 3; nt = r & 7;
        src = sw1; dst = sw1t;
    } else {                              // sw2 [512][1024]
        int r = bx - 4224;
        K = 512; N = 1024; kt = r >> 4; nt = r & 15;
        src = sw2; dst = sw2t;
    }
    int t = threadIdx.x;
    int tr = t >> 4;
    int tc = (t & 15) * 4;
#pragma unroll
    for (int i = 0; i < 4; ++i) {
        int k = kt * 64 + i * 16 + tr;
        float4 v = *reinterpret_cast<const float4*>(src + (size_t)k * N + nt * 64 + tc);
        tileT[tc + 0][i * 16 + tr] = v.x;
        tileT[tc + 1][i * 16 + tr] = v.y;
        tileT[tc + 2][i * 16 + tr] = v.z;
        tileT[tc + 3][i * 16 + tr] = v.w;
    }
    __syncthreads();
    int wr = t >> 3;
    int wc = (t & 7) * 8;
#pragma unroll
    for (int i = 0; i < 2; ++i) {
        int n = wr + i * 32;
        bf16x8 o;
#pragma unroll
        for (int j = 0; j < 8; ++j) o[j] = (short)f2b(tileT[n][wc + j]);
        *reinterpret_cast<bf16x8*>(dst + (size_t)(nt * 64 + n) * K + kt * 64 + wc) = o;
    }
}

// ---------------- router ----------------
__global__ __launch_bounds__(64) void router_kernel(
    const float* __restrict__ x, const float* __restrict__ rw,
    const float* __restrict__ sgw,
    float* __restrict__ scores,
    int* __restrict__ topk_idx,
    float* __restrict__ topk_val,
    float* __restrict__ g_shared)
{
    int token = blockIdx.x;
    int lane = threadIdx.x;
    const float* xr = x + (size_t)token * DIM;
    float acc[NEXP];
#pragma unroll
    for (int e = 0; e < NEXP; ++e) acc[e] = 0.f;
    float accg = 0.f;
    for (int d = lane; d < DIM; d += 64) {
        float xv = xr[d];
        const float* rwd = rw + d * NEXP;
#pragma unroll
        for (int e = 0; e < NEXP; ++e) acc[e] += xv * rwd[e];
        accg += xv * sgw[d];
    }
#pragma unroll
    for (int off = 32; off > 0; off >>= 1) {
#pragma unroll
        for (int e = 0; e < NEXP; ++e) acc[e] += __shfl_xor(acc[e], off, 64);
        accg += __shfl_xor(accg, off, 64);
    }
    if (lane == 0) {
        float mx = acc[0];
#pragma unroll
        for (int e = 1; e < NEXP; ++e) mx = fmaxf(mx, acc[e]);
        float p[NEXP];
        float s = 0.f;
#pragma unroll
        for (int e = 0; e < NEXP; ++e) { p[e] = expf(acc[e] - mx); s += p[e]; }
        float inv = 1.f / s;
#pragma unroll
        for (int e = 0; e < NEXP; ++e) { p[e] *= inv; scores[token * NEXP + e] = p[e]; }
        int i0 = 0; float v0 = p[0];
#pragma unroll
        for (int e = 1; e < NEXP; ++e) if (p[e] > v0) { v0 = p[e]; i0 = e; }
        int i1 = -1; float v1 = -1.f;
#pragma unroll
        for (int e = 0; e < NEXP; ++e) if (e != i0 && p[e] > v1) { v1 = p[e]; i1 = e; }
        topk_idx[2 * token] = i0; topk_idx[2 * token + 1] = i1;
        topk_val[2 * token] = v0; topk_val[2 * token + 1] = v1;
        g_shared[token] = 1.f / (1.f + expf(-accg));
    }
}

// ---------------- per-chunk expert histogram ----------------
__global__ __launch_bounds__(256) void hist_kernel(
    const int* __restrict__ topk_idx, int* __restrict__ chunk_hist)
{
    __shared__ int h[NEXP];
    int tid = threadIdx.x;
    if (tid < NEXP) h[tid] = 0;
    __syncthreads();
    int r = blockIdx.x * 256 + tid;
    atomicAdd(&h[topk_idx[r]], 1);
    __syncthreads();
    if (tid < NEXP) chunk_hist[blockIdx.x * NEXP + tid] = h[tid];
}

// ---------------- scan chunk histograms ----------------
__global__ __launch_bounds__(64) void scan_kernel(
    const int* __restrict__ chunk_hist, int* __restrict__ chunk_off,
    int* __restrict__ counts_cap, float* __restrict__ out_tail)
{
    int e = threadIdx.x;
    if (e >= NEXP) return;
    int run = 0;
    for (int b = 0; b < NCHUNK; ++b) {
        chunk_off[b * NEXP + e] = run;
        run += chunk_hist[b * NEXP + e];
    }
    counts_cap[e] = run < CAP ? run : CAP;
    out_tail[NEXP + e] = (float)((double)run / 16384.0);
}

// ---------------- deterministic slot assignment ----------------
__global__ __launch_bounds__(256) void assign_kernel(
    const int* __restrict__ topk_idx, const float* __restrict__ topk_val,
    const int* __restrict__ chunk_off,
    int* __restrict__ route_slot, int* __restrict__ slot_token)
{
    __shared__ int wave_cnt[4][NEXP];
    int tid = threadIdx.x;
    int lane = tid & 63;
    int w = tid >> 6;
    int r = blockIdx.x * 256 + tid;
    int e = topk_idx[r];
    float gate = topk_val[r];
    int rank_w = 0;
#pragma unroll
    for (int e16 = 0; e16 < NEXP; ++e16) {
        unsigned long long bal = __ballot(e == e16);
        if (e == e16) rank_w = __popcll(bal & ((1ull << lane) - 1ull));
        if (lane == 0) wave_cnt[w][e16] = __popcll(bal);
    }
    __syncthreads();
    int rank = rank_w;
#pragma unroll
    for (int w2 = 0; w2 < 3; ++w2)
        if (w2 < w) rank += wave_cnt[w2][e];
    int pos = chunk_off[blockIdx.x * NEXP + e] + rank;
    int slot = -1;
    if (pos < CAP && gate != 0.f) {
        slot = e * CAP + pos;
        slot_token[slot] = r >> 1;
    }
    route_slot[r] = slot;
}

// ---------------- importance reduction ----------------
__global__ __launch_bounds__(256) void importance_kernel(
    const float* __restrict__ scores, float* __restrict__ out_tail)
{
    __shared__ float red[256];
    int e = blockIdx.x;
    float s = 0.f;
    for (int t = threadIdx.x; t < N_TOK; t += 256) s += scores[t * NEXP + e];
    red[threadIdx.x] = s;
    __syncthreads();
    for (int st = 128; st > 0; st >>= 1) {
        if (threadIdx.x < st) red[threadIdx.x] += red[threadIdx.x + st];
        __syncthreads();
    }
    if (threadIdx.x == 0) out_tail[e] = red[0] / (float)N_TOK;
}

// ================= MFMA grouped GEMM 1: h = gelu(X @ W1) =================
// 128x128 tile, BK=32, 4 waves. 2-phase double-buffered LDS (T3-min),
// XCD-chunked block swizzle (T1), n-block innermost.
#define G1_NWG ((NEXP * 10 + N_TOK / 128) * (FDIM / 128))   /* 896 */
__global__ __launch_bounds__(256) void gemm1_mfma(
    const ushort_t* __restrict__ x_bf,
    const ushort_t* __restrict__ w1t,     // [16][FDIM][DIM] bf16 n-major
    const ushort_t* __restrict__ sw1t,    // [FDIM][DIM]
    const int* __restrict__ slot_token,
    const int* __restrict__ counts_cap,
    ushort_t* __restrict__ h_buf)         // [TOTROW][FDIM] bf16
{
    __shared__ ushort_t As[2][128 * 32];
    __shared__ ushort_t Bs[2][128 * 32];

    // T1: bijective XCD-chunked swizzle (nwg % 8 == 0)
    int flat = blockIdx.x;
    int wg = (flat & 7) * (G1_NWG / 8) + (flat >> 3);
    int by = wg & 3;            // n-block innermost
    int bxg = wg >> 2;

    int g, rb;
    if (bxg < NEXP * 10) { g = bxg / 10; rb = bxg % 10; }
    else { g = NEXP; rb = bxg - NEXP * 10; }
    int Mg = (g < NEXP) ? counts_cap[g] : N_TOK;
    int m0 = rb * 128;
    if (m0 >= Mg) return;
    const ushort_t* Bt = (g < NEXP) ? (w1t + (size_t)g * DIM * FDIM) : sw1t;
    int n0 = by * 128;
    int t = threadIdx.x;

    const ushort_t* asrc[2];
#pragma unroll
    for (int i = 0; i < 2; ++i) {
        int row = m0 + i * 64 + (t >> 2);
        int rc = row < Mg ? row : (Mg - 1);
        int tok = (g < NEXP) ? slot_token[g * CAP + rc] : rc;
        asrc[i] = x_bf + (size_t)tok * DIM + (t & 3) * 8;
    }
    const ushort_t* bsrc[2];
#pragma unroll
    for (int i = 0; i < 2; ++i) {
        int col = n0 + i * 64 + (t >> 2);
        bsrc[i] = Bt + (size_t)col * DIM + (t & 3) * 8;
    }

    int lane = t & 63;
    int w = t >> 6;
    int wm = (w & 1) * 64, wn = (w >> 1) * 64;
    int l15 = lane & 15, q = lane >> 4;

    f32x4 acc[4][4];
#pragma unroll
    for (int m = 0; m < 4; ++m)
#pragma unroll
        for (int n = 0; n < 4; ++n) acc[m][n] = (f32x4){0.f, 0.f, 0.f, 0.f};

    // prologue: stage tile 0 into buf 0
    gload16(asrc[0], &As[0][t * 8]);
    gload16(asrc[1], &As[0][t * 8 + 2048]);
    gload16(bsrc[0], &Bs[0][t * 8]);
    gload16(bsrc[1], &Bs[0][t * 8 + 2048]);
    __syncthreads();

    int cur = 0;
    for (int k0 = 32; k0 <= DIM; k0 += 32) {
        if (k0 < DIM) {   // stage next tile into other buffer (flies during MFMA)
            int nb = cur ^ 1;
            gload16(asrc[0] + k0, &As[nb][t * 8]);
            gload16(asrc[1] + k0, &As[nb][t * 8 + 2048]);
            gload16(bsrc[0] + k0, &Bs[nb][t * 8]);
            gload16(bsrc[1] + k0, &Bs[nb][t * 8 + 2048]);
        }
        bf16x8 af[4], bfr[4];
#pragma unroll
        for (int m = 0; m < 4; ++m)
            af[m] = *reinterpret_cast<const bf16x8*>(&As[cur][(wm + m * 16 + l15) * 32 + q * 8]);
#pragma unroll
        for (int n = 0; n < 4; ++n)
            bfr[n] = *reinterpret_cast<const bf16x8*>(&Bs[cur][(wn + n * 16 + l15) * 32 + q * 8]);
#pragma unroll
        for (int m = 0; m < 4; ++m)
#pragma unroll
            for (int n = 0; n < 4; ++n)
                acc[m][n] = __builtin_amdgcn_mfma_f32_16x16x32_bf16(
                    af[m], bfr[n], acc[m][n], 0, 0, 0);
        __syncthreads();   // drains next-tile vmcnt + barrier (one per K-step)
        cur ^= 1;
    }

    size_t obase = (g < NEXP) ? ((size_t)g * CAP) : (size_t)ECAP;
#pragma unroll
    for (int m = 0; m < 4; ++m) {
#pragma unroll
        for (int r = 0; r < 4; ++r) {
            int grow = m0 + wm + m * 16 + q * 4 + r;
            if (grow < Mg) {
                ushort_t* orow = h_buf + (obase + grow) * FDIM + n0 + wn + l15;
#pragma unroll
                for (int n = 0; n < 4; ++n)
                    orow[n * 16] = f2b(gelu_exact(acc[m][n][r]));
            }
        }
    }
}

// ================= MFMA grouped GEMM 2: out = H @ W2 =================
#define G2_NWG ((NEXP * 10 + N_TOK / 128) * (DIM / 128))    /* 1792 */
__global__ __launch_bounds__(256) void gemm2_mfma(
    const ushort_t* __restrict__ h_buf,
    const ushort_t* __restrict__ w2t,     // [16][DIM][FDIM] bf16 n-major
    const ushort_t* __restrict__ sw2t,    // [DIM][FDIM]
    const int* __restrict__ counts_cap,
    const float* __restrict__ g_shared,
    ushort_t* __restrict__ out_buf,       // [ECAP][DIM] bf16
    float* __restrict__ y)                // [N_TOK][DIM]
{
    __shared__ ushort_t As[2][128 * 32];
    __shared__ ushort_t Bs[2][128 * 32];

    int flat = blockIdx.x;
    int wg = (flat & 7) * (G2_NWG / 8) + (flat >> 3);
    int by = wg & 7;
    int bxg = wg >> 3;

    int g, rb;
    if (bxg < NEXP * 10) { g = bxg / 10; rb = bxg % 10; }
    else { g = NEXP; rb = bxg - NEXP * 10; }
    int Mg = (g < NEXP) ? counts_cap[g] : N_TOK;
    int m0 = rb * 128;
    if (m0 >= Mg) return;
    const ushort_t* Bt = (g < NEXP) ? (w2t + (size_t)g * FDIM * DIM) : sw2t;
    size_t abase = (g < NEXP) ? ((size_t)g * CAP) : (size_t)ECAP;
    int n0 = by * 128;
    int t = threadIdx.x;

    const ushort_t* asrc[2];
#pragma unroll
    for (int i = 0; i < 2; ++i) {
        int row = m0 + i * 64 + (t >> 2);
        int rc = row < Mg ? row : (Mg - 1);
        asrc[i] = h_buf + (abase + rc) * FDIM + (t & 3) * 8;
    }
    const ushort_t* bsrc[2];
#pragma unroll
    for (int i = 0; i < 2; ++i) {
        int col = n0 + i * 64 + (t >> 2);
        bsrc[i] = Bt + (size_t)col * FDIM + (t & 3) * 8;
    }

    int lane = t & 63;
    int w = t >> 6;
    int wm = (w & 1) * 64, wn = (w >> 1) * 64;
    int l15 = lane & 15, q = lane >> 4;

    f32x4 acc[4][4];
#pragma unroll
    for (int m = 0; m < 4; ++m)
#pragma unroll
        for (int n = 0; n < 4; ++n) acc[m][n] = (f32x4){0.f, 0.f, 0.f, 0.f};

    gload16(asrc[0], &As[0][t * 8]);
    gload16(asrc[1], &As[0][t * 8 + 2048]);
    gload16(bsrc[0], &Bs[0][t * 8]);
    gload16(bsrc[1], &Bs[0][t * 8 + 2048]);
    __syncthreads();

    int cur = 0;
    for (int k0 = 32; k0 <= FDIM; k0 += 32) {
        if (k0 < FDIM) {
            int nb = cur ^ 1;
            gload16(asrc[0] + k0, &As[nb][t * 8]);
            gload16(asrc[1] + k0, &As[nb][t * 8 + 2048]);
            gload16(bsrc[0] + k0, &Bs[nb][t * 8]);
            gload16(bsrc[1] + k0, &Bs[nb][t * 8 + 2048]);
        }
        bf16x8 af[4], bfr[4];
#pragma unroll
        for (int m = 0; m < 4; ++m)
            af[m] = *reinterpret_cast<const bf16x8*>(&As[cur][(wm + m * 16 + l15) * 32 + q * 8]);
#pragma unroll
        for (int n = 0; n < 4; ++n)
            bfr[n] = *reinterpret_cast<const bf16x8*>(&Bs[cur][(wn + n * 16 + l15) * 32 + q * 8]);
#pragma unroll
        for (int m = 0; m < 4; ++m)
#pragma unroll
            for (int n = 0; n < 4; ++n)
                acc[m][n] = __builtin_amdgcn_mfma_f32_16x16x32_bf16(
                    af[m], bfr[n], acc[m][n], 0, 0, 0);
        __syncthreads();
        cur ^= 1;
    }

    if (g < NEXP) {
#pragma unroll
        for (int m = 0; m < 4; ++m) {
#pragma unroll
            for (int r = 0; r < 4; ++r) {
                int grow = m0 + wm + m * 16 + q * 4 + r;
                if (grow < Mg) {
                    ushort_t* orow = out_buf + ((size_t)g * CAP + grow) * DIM + n0 + wn + l15;
#pragma unroll
                    for (int n = 0; n < 4; ++n)
                        orow[n * 16] = f2b(acc[m][n][r]);
                }
            }
        }
    } else {
#pragma unroll
        for (int m = 0; m < 4; ++m) {
#pragma unroll
            for (int r = 0; r < 4; ++r) {
                int tok = m0 + wm + m * 16 + q * 4 + r;
                float gs = g_shared[tok];
                float* orow = y + (size_t)tok * DIM + n0 + wn + l15;
#pragma unroll
                for (int n = 0; n < 4; ++n)
                    orow[n * 16] = gs * acc[m][n][r];
            }
        }
    }
}

// ---------------- combine: y += sum(gate * expert_out) ----------------
__global__ __launch_bounds__(256) void combine_kernel(
    const ushort_t* __restrict__ out_buf,
    const int* __restrict__ route_slot, const float* __restrict__ topk_val,
    float* __restrict__ y)
{
    int token = blockIdx.x;
    int c = threadIdx.x * 4;
    float* yp = y + (size_t)token * DIM + c;
    float4 acc = *reinterpret_cast<float4*>(yp);
#pragma unroll
    for (int k = 0; k < 2; ++k) {
        int s = route_slot[2 * token + k];
        if (s >= 0) {
            float gate = topk_val[2 * token + k];
            ushort4 rv = *reinterpret_cast<const ushort4*>(out_buf + (size_t)s * DIM + c);
            acc.x += gate * bf2f(rv.x); acc.y += gate * bf2f(rv.y);
            acc.z += gate * bf2f(rv.z); acc.w += gate * bf2f(rv.w);
        }
    }
    *reinterpret_cast<float4*>(yp) = acc;
}

extern "C" void kernel_launch(void* const* d_in, const int* in_sizes, int n_in,
                              void* d_out, int out_size, void* d_ws, size_t ws_size,
                              hipStream_t stream) {
    const float* x   = (const float*)d_in[0];
    const float* rw  = (const float*)d_in[1];
    const float* sgw = (const float*)d_in[2];
    const float* w1  = (const float*)d_in[3];
    const float* w2  = (const float*)d_in[4];
    const float* sw1 = (const float*)d_in[5];
    const float* sw2 = (const float*)d_in[6];
    float* y = (float*)d_out;
    float* out_tail = y + (size_t)N_TOK * DIM;

    size_t off = 0;
    char* wsb = (char*)d_ws;
    auto alloc = [&](size_t bytes) -> void* {
        void* p = wsb + off;
        off += (bytes + 255) & ~(size_t)255;
        return p;
    };
    float*    scores     = (float*)alloc((size_t)N_TOK * NEXP * 4);
    int*      topk_idx   = (int*)alloc((size_t)NROUTE * 4);
    float*    topk_val   = (float*)alloc((size_t)NROUTE * 4);
    float*    g_shared   = (float*)alloc((size_t)N_TOK * 4);
    int*      chunk_hist = (int*)alloc((size_t)NCHUNK * NEXP * 4);
    int*      chunk_off  = (int*)alloc((size_t)NCHUNK * NEXP * 4);
    int*      counts_cap = (int*)alloc((size_t)NEXP * 4);
    int*      route_slot = (int*)alloc((size_t)NROUTE * 4);
    int*      slot_token = (int*)alloc((size_t)ECAP * 4);
    ushort_t* x_bf       = (ushort_t*)alloc((size_t)N_TOK * DIM * 2);
    ushort_t* w1t        = (ushort_t*)alloc((size_t)NEXP * DIM * FDIM * 2);
    ushort_t* w2t        = (ushort_t*)alloc((size_t)NEXP * DIM * FDIM * 2);
    ushort_t* sw1t       = (ushort_t*)alloc((size_t)DIM * FDIM * 2);
    ushort_t* sw2t       = (ushort_t*)alloc((size_t)DIM * FDIM * 2);
    ushort_t* h_buf      = (ushort_t*)alloc((size_t)TOTROW * FDIM * 2);
    ushort_t* out_buf    = (ushort_t*)alloc((size_t)ECAP * DIM * 2);
    (void)ws_size; (void)in_sizes; (void)n_in; (void)out_size;

    convert_x_kernel<<<N_TOK * DIM / 2048, 256, 0, stream>>>(x, x_bf);
    transpose_w_kernel<<<4352, 256, 0, stream>>>(w1, w2, sw1, sw2, w1t, w2t, sw1t, sw2t);
    router_kernel<<<N_TOK, 64, 0, stream>>>(x, rw, sgw, scores, topk_idx, topk_val, g_shared);
    hist_kernel<<<NCHUNK, 256, 0, stream>>>(topk_idx, chunk_hist);
    scan_kernel<<<1, 64, 0, stream>>>(chunk_hist, chunk_off, counts_cap, out_tail);
    assign_kernel<<<NCHUNK, 256, 0, stream>>>(topk_idx, topk_val, chunk_off, route_slot, slot_token);
    importance_kernel<<<NEXP, 256, 0, stream>>>(scores, out_tail);

    gemm1_mfma<<<G1_NWG, 256, 0, stream>>>(x_bf, w1t, sw1t, slot_token, counts_cap, h_buf);
    gemm2_mfma<<<G2_NWG, 256, 0, stream>>>(h_buf, w2t, sw2t, counts_cap, g_shared, out_buf, y);

    combine_kernel<<<N_TOK, 256, 0, stream>>>(out_buf, route_slot, topk_val, y);
}

// Round 5
// 209.495 us; speedup vs baseline: 1.0890x; 1.0890x over previous
//
#include <hip/hip_runtime.h>
#include <hip/hip_bf16.h>
#include <math.h>

#define N_TOK 8192
#define DIM 1024
#define NEXP 16
#define CAP 1280
#define FDIM 512
#define NROUTE (N_TOK * 2)
#define NCHUNK 64
#define ECAP (NEXP * CAP)        /* 20480 */
#define TOTROW (ECAP + N_TOK)    /* 28672 */

typedef __hip_bfloat16 bf16;
typedef unsigned short ushort_t;
typedef __attribute__((ext_vector_type(8))) short bf16x8;
typedef __attribute__((ext_vector_type(4))) float f32x4;

__device__ __forceinline__ float gelu_exact(float x) {
    return 0.5f * x * (1.0f + erff(x * 0.70710678118654752f));
}

__device__ __forceinline__ float bf2f(unsigned short u) {
    union { float f; unsigned int i; } v; v.i = ((unsigned int)u) << 16; return v.f;
}

__device__ __forceinline__ unsigned short f2b(float f) {
    union { __hip_bfloat16 h; unsigned short u; } v;
    v.h = __float2bfloat16(f);
    return v.u;
}

__device__ __forceinline__ void gload16(const void* g, void* l) {
    __builtin_amdgcn_global_load_lds(
        (const __attribute__((address_space(1))) unsigned int*)g,
        (__attribute__((address_space(3))) unsigned int*)l,
        16, 0, 0);
}

// swizzled LDS tile mapping (rule #21, both-sides): tile is [128 rows][4 chunks
// of 8 bf16]. addr16(r,q) = (r>>1)*8 + ((r&1)<<2) + (q ^ ((r>>1)&3)).
// Staging keeps LDS dest linear (slot s = thread t) and permutes the SOURCE
// chunk: lr(s) = 2*(s>>3) | ((s>>2)&1), qq(s) = (s&3) ^ ((s>>3)&3).
__device__ __forceinline__ int swz_addr16(int r, int q) {
    return ((r >> 1) << 3) + ((r & 1) << 2) + (q ^ ((r >> 1) & 3));
}

// ---------------- convert x fp32 -> bf16 ----------------
__global__ __launch_bounds__(256) void convert_x_kernel(
    const float* __restrict__ x, ushort_t* __restrict__ x_bf)
{
    int i = (blockIdx.x * 256 + threadIdx.x) * 8;
    float4 a = *reinterpret_cast<const float4*>(x + i);
    float4 b = *reinterpret_cast<const float4*>(x + i + 4);
    bf16x8 o;
    o[0] = (short)f2b(a.x); o[1] = (short)f2b(a.y);
    o[2] = (short)f2b(a.z); o[3] = (short)f2b(a.w);
    o[4] = (short)f2b(b.x); o[5] = (short)f2b(b.y);
    o[6] = (short)f2b(b.z); o[7] = (short)f2b(b.w);
    *reinterpret_cast<bf16x8*>(x_bf + i) = o;
}

// ---------------- transpose+convert weights: fp32 [K][N] -> bf16 [N][K] ----------------
__global__ __launch_bounds__(256) void transpose_w_kernel(
    const float* __restrict__ w1, const float* __restrict__ w2,
    const float* __restrict__ sw1, const float* __restrict__ sw2,
    ushort_t* __restrict__ w1t, ushort_t* __restrict__ w2t,
    ushort_t* __restrict__ sw1t, ushort_t* __restrict__ sw2t)
{
    __shared__ float tileT[64][65];   // [n][k]
    int bx = blockIdx.x;
    const float* src; ushort_t* dst; int K, N, kt, nt;
    if (bx < 2048) {                      // w1: per-expert [1024][512]
        int e = bx >> 7, r = bx & 127;
        K = 1024; N = 512; kt = r >> 3; nt = r & 7;
        src = w1 + (size_t)e * K * N; dst = w1t + (size_t)e * K * N;
    } else if (bx < 4096) {               // w2: per-expert [512][1024]
        int b2 = bx - 2048, e = b2 >> 7, r = b2 & 127;
        K = 512; N = 1024; kt = r >> 4; nt = r & 15;
        src = w2 + (size_t)e * K * N; dst = w2t + (size_t)e * K * N;
    } else if (bx < 4224) {               // sw1 [1024][512]
        int r = bx - 4096;
        K = 1024; N = 512; kt = r >> 3; nt = r & 7;
        src = sw1; dst = sw1t;
    } else {                              // sw2 [512][1024]
        int r = bx - 4224;
        K = 512; N = 1024; kt = r >> 4; nt = r & 15;
        src = sw2; dst = sw2t;
    }
    int t = threadIdx.x;
    int tr = t >> 4;
    int tc = (t & 15) * 4;
#pragma unroll
    for (int i = 0; i < 4; ++i) {
        int k = kt * 64 + i * 16 + tr;
        float4 v = *reinterpret_cast<const float4*>(src + (size_t)k * N + nt * 64 + tc);
        tileT[tc + 0][i * 16 + tr] = v.x;
        tileT[tc + 1][i * 16 + tr] = v.y;
        tileT[tc + 2][i * 16 + tr] = v.z;
        tileT[tc + 3][i * 16 + tr] = v.w;
    }
    __syncthreads();
    int wr = t >> 3;
    int wc = (t & 7) * 8;
#pragma unroll
    for (int i = 0; i < 2; ++i) {
        int n = wr + i * 32;
        bf16x8 o;
#pragma unroll
        for (int j = 0; j < 8; ++j) o[j] = (short)f2b(tileT[n][wc + j]);
        *reinterpret_cast<bf16x8*>(dst + (size_t)(nt * 64 + n) * K + kt * 64 + wc) = o;
    }
}

// ---------------- router ----------------
__global__ __launch_bounds__(64) void router_kernel(
    const float* __restrict__ x, const float* __restrict__ rw,
    const float* __restrict__ sgw,
    float* __restrict__ scores,
    int* __restrict__ topk_idx,
    float* __restrict__ topk_val,
    float* __restrict__ g_shared)
{
    int token = blockIdx.x;
    int lane = threadIdx.x;
    const float* xr = x + (size_t)token * DIM;
    float acc[NEXP];
#pragma unroll
    for (int e = 0; e < NEXP; ++e) acc[e] = 0.f;
    float accg = 0.f;
    for (int d = lane; d < DIM; d += 64) {
        float xv = xr[d];
        const float* rwd = rw + d * NEXP;
#pragma unroll
        for (int e = 0; e < NEXP; ++e) acc[e] += xv * rwd[e];
        accg += xv * sgw[d];
    }
#pragma unroll
    for (int off = 32; off > 0; off >>= 1) {
#pragma unroll
        for (int e = 0; e < NEXP; ++e) acc[e] += __shfl_xor(acc[e], off, 64);
        accg += __shfl_xor(accg, off, 64);
    }
    if (lane == 0) {
        float mx = acc[0];
#pragma unroll
        for (int e = 1; e < NEXP; ++e) mx = fmaxf(mx, acc[e]);
        float p[NEXP];
        float s = 0.f;
#pragma unroll
        for (int e = 0; e < NEXP; ++e) { p[e] = expf(acc[e] - mx); s += p[e]; }
        float inv = 1.f / s;
#pragma unroll
        for (int e = 0; e < NEXP; ++e) { p[e] *= inv; scores[token * NEXP + e] = p[e]; }
        int i0 = 0; float v0 = p[0];
#pragma unroll
        for (int e = 1; e < NEXP; ++e) if (p[e] > v0) { v0 = p[e]; i0 = e; }
        int i1 = -1; float v1 = -1.f;
#pragma unroll
        for (int e = 0; e < NEXP; ++e) if (e != i0 && p[e] > v1) { v1 = p[e]; i1 = e; }
        topk_idx[2 * token] = i0; topk_idx[2 * token + 1] = i1;
        topk_val[2 * token] = v0; topk_val[2 * token + 1] = v1;
        g_shared[token] = 1.f / (1.f + expf(-accg));
    }
}

// ---------------- per-chunk expert histogram ----------------
__global__ __launch_bounds__(256) void hist_kernel(
    const int* __restrict__ topk_idx, int* __restrict__ chunk_hist)
{
    __shared__ int h[NEXP];
    int tid = threadIdx.x;
    if (tid < NEXP) h[tid] = 0;
    __syncthreads();
    int r = blockIdx.x * 256 + tid;
    atomicAdd(&h[topk_idx[r]], 1);
    __syncthreads();
    if (tid < NEXP) chunk_hist[blockIdx.x * NEXP + tid] = h[tid];
}

// ---------------- scan chunk histograms ----------------
__global__ __launch_bounds__(64) void scan_kernel(
    const int* __restrict__ chunk_hist, int* __restrict__ chunk_off,
    int* __restrict__ counts_cap, float* __restrict__ out_tail)
{
    int e = threadIdx.x;
    if (e >= NEXP) return;
    int run = 0;
    for (int b = 0; b < NCHUNK; ++b) {
        chunk_off[b * NEXP + e] = run;
        run += chunk_hist[b * NEXP + e];
    }
    counts_cap[e] = run < CAP ? run : CAP;
    out_tail[NEXP + e] = (float)((double)run / 16384.0);
}

// ---------------- deterministic slot assignment ----------------
__global__ __launch_bounds__(256) void assign_kernel(
    const int* __restrict__ topk_idx, const float* __restrict__ topk_val,
    const int* __restrict__ chunk_off,
    int* __restrict__ route_slot, int* __restrict__ slot_token)
{
    __shared__ int wave_cnt[4][NEXP];
    int tid = threadIdx.x;
    int lane = tid & 63;
    int w = tid >> 6;
    int r = blockIdx.x * 256 + tid;
    int e = topk_idx[r];
    float gate = topk_val[r];
    int rank_w = 0;
#pragma unroll
    for (int e16 = 0; e16 < NEXP; ++e16) {
        unsigned long long bal = __ballot(e == e16);
        if (e == e16) rank_w = __popcll(bal & ((1ull << lane) - 1ull));
        if (lane == 0) wave_cnt[w][e16] = __popcll(bal);
    }
    __syncthreads();
    int rank = rank_w;
#pragma unroll
    for (int w2 = 0; w2 < 3; ++w2)
        if (w2 < w) rank += wave_cnt[w2][e];
    int pos = chunk_off[blockIdx.x * NEXP + e] + rank;
    int slot = -1;
    if (pos < CAP && gate != 0.f) {
        slot = e * CAP + pos;
        slot_token[slot] = r >> 1;
    }
    route_slot[r] = slot;
}

// ---------------- importance reduction ----------------
__global__ __launch_bounds__(256) void importance_kernel(
    const float* __restrict__ scores, float* __restrict__ out_tail)
{
    __shared__ float red[256];
    int e = blockIdx.x;
    float s = 0.f;
    for (int t = threadIdx.x; t < N_TOK; t += 256) s += scores[t * NEXP + e];
    red[threadIdx.x] = s;
    __syncthreads();
    for (int st = 128; st > 0; st >>= 1) {
        if (threadIdx.x < st) red[threadIdx.x] += red[threadIdx.x + st];
        __syncthreads();
    }
    if (threadIdx.x == 0) out_tail[e] = red[0] / (float)N_TOK;
}

// ================= MFMA grouped GEMM 1: h = gelu(X @ W1) =================
// 128x128 tile, BK=32, 4 waves. 3-buffer LDS pipeline, loads 2 K-steps
// ahead, counted vmcnt(4) (T3+T4), swizzled LDS (T2), setprio (T5),
// XCD-chunked swizzle (T1).
#define G1_NWG ((NEXP * 10 + N_TOK / 128) * (FDIM / 128))   /* 896 */
__global__ __launch_bounds__(256) void gemm1_mfma(
    const ushort_t* __restrict__ x_bf,
    const ushort_t* __restrict__ w1t,     // [16][FDIM][DIM] bf16 n-major
    const ushort_t* __restrict__ sw1t,    // [FDIM][DIM]
    const int* __restrict__ slot_token,
    const int* __restrict__ counts_cap,
    ushort_t* __restrict__ h_buf)         // [TOTROW][FDIM] bf16
{
    __shared__ ushort_t As[3][128 * 32];
    __shared__ ushort_t Bs[3][128 * 32];

    int flat = blockIdx.x;
    int wg = (flat & 7) * (G1_NWG / 8) + (flat >> 3);
    int by = wg & 3;
    int bxg = wg >> 2;

    int g, rb;
    if (bxg < NEXP * 10) { g = bxg / 10; rb = bxg % 10; }
    else { g = NEXP; rb = bxg - NEXP * 10; }
    int Mg = (g < NEXP) ? counts_cap[g] : N_TOK;
    int m0 = rb * 128;
    if (m0 >= Mg) return;
    const ushort_t* Bt = (g < NEXP) ? (w1t + (size_t)g * DIM * FDIM) : sw1t;
    int n0 = by * 128;
    int t = threadIdx.x;

    // staging sources: linear LDS slot s -> (row lr, chunk qq), source-permuted
    const ushort_t* asrc[2];
    const ushort_t* bsrc[2];
#pragma unroll
    for (int i = 0; i < 2; ++i) {
        int s = t + i * 256;
        int lr = ((s >> 3) << 1) | ((s >> 2) & 1);
        int qq = (s & 3) ^ ((s >> 3) & 3);
        int row = m0 + lr;
        int rc = row < Mg ? row : (Mg - 1);
        int tok = (g < NEXP) ? slot_token[g * CAP + rc] : rc;
        asrc[i] = x_bf + (size_t)tok * DIM + qq * 8;
        bsrc[i] = Bt + (size_t)(n0 + lr) * DIM + qq * 8;
    }

    int lane = t & 63;
    int w = t >> 6;
    int wm = (w & 1) * 64, wn = (w >> 1) * 64;
    int l15 = lane & 15, q = lane >> 4;

    // precomputed swizzled read offsets (elements)
    int aoff[4], boff[4];
#pragma unroll
    for (int m = 0; m < 4; ++m) aoff[m] = swz_addr16(wm + m * 16 + l15, q) << 3;
#pragma unroll
    for (int n = 0; n < 4; ++n) boff[n] = swz_addr16(wn + n * 16 + l15, q) << 3;

    f32x4 acc[4][4];
#pragma unroll
    for (int m = 0; m < 4; ++m)
#pragma unroll
        for (int n = 0; n < 4; ++n) acc[m][n] = (f32x4){0.f, 0.f, 0.f, 0.f};

    auto STAGE = [&](int buf, int koff) {
        gload16(asrc[0] + koff, &As[buf][t * 8]);
        gload16(asrc[1] + koff, &As[buf][t * 8 + 2048]);
        gload16(bsrc[0] + koff, &Bs[buf][t * 8]);
        gload16(bsrc[1] + koff, &Bs[buf][t * 8 + 2048]);
    };

    const int NSTEP = DIM / 32;   // 32
    STAGE(0, 0);
    STAGE(1, 32);
    asm volatile("s_waitcnt vmcnt(4)" ::: "memory");
    __builtin_amdgcn_s_barrier();
    asm volatile("" ::: "memory");

    int cur = 0, b2 = 2;
    for (int kt = 0; kt < NSTEP; ++kt) {
        if (kt + 2 < NSTEP) STAGE(b2, (kt + 2) * 32);
        const ushort_t* asb = &As[cur][0];
        const ushort_t* bsb = &Bs[cur][0];
        bf16x8 af[4], bfr[4];
#pragma unroll
        for (int m = 0; m < 4; ++m)
            af[m] = *reinterpret_cast<const bf16x8*>(asb + aoff[m]);
#pragma unroll
        for (int n = 0; n < 4; ++n)
            bfr[n] = *reinterpret_cast<const bf16x8*>(bsb + boff[n]);
        __builtin_amdgcn_s_setprio(1);
#pragma unroll
        for (int m = 0; m < 4; ++m)
#pragma unroll
            for (int n = 0; n < 4; ++n)
                acc[m][n] = __builtin_amdgcn_mfma_f32_16x16x32_bf16(
                    af[m], bfr[n], acc[m][n], 0, 0, 0);
        __builtin_amdgcn_s_setprio(0);
        if (kt + 1 < NSTEP) {
            if (kt + 2 < NSTEP) asm volatile("s_waitcnt vmcnt(4)" ::: "memory");
            else                asm volatile("s_waitcnt vmcnt(0)" ::: "memory");
            __builtin_amdgcn_s_barrier();
            asm volatile("" ::: "memory");
        }
        cur = (cur == 2) ? 0 : cur + 1;
        b2  = (b2 == 2) ? 0 : b2 + 1;
    }

    size_t obase = (g < NEXP) ? ((size_t)g * CAP) : (size_t)ECAP;
#pragma unroll
    for (int m = 0; m < 4; ++m) {
#pragma unroll
        for (int r = 0; r < 4; ++r) {
            int grow = m0 + wm + m * 16 + q * 4 + r;
            if (grow < Mg) {
                ushort_t* orow = h_buf + (obase + grow) * FDIM + n0 + wn + l15;
#pragma unroll
                for (int n = 0; n < 4; ++n)
                    orow[n * 16] = f2b(gelu_exact(acc[m][n][r]));
            }
        }
    }
}

// ================= MFMA grouped GEMM 2: out = H @ W2 =================
#define G2_NWG ((NEXP * 10 + N_TOK / 128) * (DIM / 128))    /* 1792 */
__global__ __launch_bounds__(256) void gemm2_mfma(
    const ushort_t* __restrict__ h_buf,
    const ushort_t* __restrict__ w2t,     // [16][DIM][FDIM] bf16 n-major
    const ushort_t* __restrict__ sw2t,    // [DIM][FDIM]
    const int* __restrict__ counts_cap,
    const float* __restrict__ g_shared,
    ushort_t* __restrict__ out_buf,       // [ECAP][DIM] bf16
    float* __restrict__ y)                // [N_TOK][DIM]
{
    __shared__ ushort_t As[3][128 * 32];
    __shared__ ushort_t Bs[3][128 * 32];

    int flat = blockIdx.x;
    int wg = (flat & 7) * (G2_NWG / 8) + (flat >> 3);
    int by = wg & 7;
    int bxg = wg >> 3;

    int g, rb;
    if (bxg < NEXP * 10) { g = bxg / 10; rb = bxg % 10; }
    else { g = NEXP; rb = bxg - NEXP * 10; }
    int Mg = (g < NEXP) ? counts_cap[g] : N_TOK;
    int m0 = rb * 128;
    if (m0 >= Mg) return;
    const ushort_t* Bt = (g < NEXP) ? (w2t + (size_t)g * FDIM * DIM) : sw2t;
    size_t abase = (g < NEXP) ? ((size_t)g * CAP) : (size_t)ECAP;
    int n0 = by * 128;
    int t = threadIdx.x;

    const ushort_t* asrc[2];
    const ushort_t* bsrc[2];
#pragma unroll
    for (int i = 0; i < 2; ++i) {
        int s = t + i * 256;
        int lr = ((s >> 3) << 1) | ((s >> 2) & 1);
        int qq = (s & 3) ^ ((s >> 3) & 3);
        int row = m0 + lr;
        int rc = row < Mg ? row : (Mg - 1);
        asrc[i] = h_buf + (abase + rc) * FDIM + qq * 8;
        bsrc[i] = Bt + (size_t)(n0 + lr) * FDIM + qq * 8;
    }

    int lane = t & 63;
    int w = t >> 6;
    int wm = (w & 1) * 64, wn = (w >> 1) * 64;
    int l15 = lane & 15, q = lane >> 4;

    int aoff[4], boff[4];
#pragma unroll
    for (int m = 0; m < 4; ++m) aoff[m] = swz_addr16(wm + m * 16 + l15, q) << 3;
#pragma unroll
    for (int n = 0; n < 4; ++n) boff[n] = swz_addr16(wn + n * 16 + l15, q) << 3;

    f32x4 acc[4][4];
#pragma unroll
    for (int m = 0; m < 4; ++m)
#pragma unroll
        for (int n = 0; n < 4; ++n) acc[m][n] = (f32x4){0.f, 0.f, 0.f, 0.f};

    auto STAGE = [&](int buf, int koff) {
        gload16(asrc[0] + koff, &As[buf][t * 8]);
        gload16(asrc[1] + koff, &As[buf][t * 8 + 2048]);
        gload16(bsrc[0] + koff, &Bs[buf][t * 8]);
        gload16(bsrc[1] + koff, &Bs[buf][t * 8 + 2048]);
    };

    const int NSTEP = FDIM / 32;  // 16
    STAGE(0, 0);
    STAGE(1, 32);
    asm volatile("s_waitcnt vmcnt(4)" ::: "memory");
    __builtin_amdgcn_s_barrier();
    asm volatile("" ::: "memory");

    int cur = 0, b2 = 2;
    for (int kt = 0; kt < NSTEP; ++kt) {
        if (kt + 2 < NSTEP) STAGE(b2, (kt + 2) * 32);
        const ushort_t* asb = &As[cur][0];
        const ushort_t* bsb = &Bs[cur][0];
        bf16x8 af[4], bfr[4];
#pragma unroll
        for (int m = 0; m < 4; ++m)
            af[m] = *reinterpret_cast<const bf16x8*>(asb + aoff[m]);
#pragma unroll
        for (int n = 0; n < 4; ++n)
            bfr[n] = *reinterpret_cast<const bf16x8*>(bsb + boff[n]);
        __builtin_amdgcn_s_setprio(1);
#pragma unroll
        for (int m = 0; m < 4; ++m)
#pragma unroll
            for (int n = 0; n < 4; ++n)
                acc[m][n] = __builtin_amdgcn_mfma_f32_16x16x32_bf16(
                    af[m], bfr[n], acc[m][n], 0, 0, 0);
        __builtin_amdgcn_s_setprio(0);
        if (kt + 1 < NSTEP) {
            if (kt + 2 < NSTEP) asm volatile("s_waitcnt vmcnt(4)" ::: "memory");
            else                asm volatile("s_waitcnt vmcnt(0)" ::: "memory");
            __builtin_amdgcn_s_barrier();
            asm volatile("" ::: "memory");
        }
        cur = (cur == 2) ? 0 : cur + 1;
        b2  = (b2 == 2) ? 0 : b2 + 1;
    }

    if (g < NEXP) {
#pragma unroll
        for (int m = 0; m < 4; ++m) {
#pragma unroll
            for (int r = 0; r < 4; ++r) {
                int grow = m0 + wm + m * 16 + q * 4 + r;
                if (grow < Mg) {
                    ushort_t* orow = out_buf + ((size_t)g * CAP + grow) * DIM + n0 + wn + l15;
#pragma unroll
                    for (int n = 0; n < 4; ++n)
                        orow[n * 16] = f2b(acc[m][n][r]);
                }
            }
        }
    } else {
#pragma unroll
        for (int m = 0; m < 4; ++m) {
#pragma unroll
            for (int r = 0; r < 4; ++r) {
                int tok = m0 + wm + m * 16 + q * 4 + r;
                float gs = g_shared[tok];
                float* orow = y + (size_t)tok * DIM + n0 + wn + l15;
#pragma unroll
                for (int n = 0; n < 4; ++n)
                    orow[n * 16] = gs * acc[m][n][r];
            }
        }
    }
}

// ---------------- combine: y += sum(gate * expert_out) ----------------
__global__ __launch_bounds__(256) void combine_kernel(
    const ushort_t* __restrict__ out_buf,
    const int* __restrict__ route_slot, const float* __restrict__ topk_val,
    float* __restrict__ y)
{
    int token = blockIdx.x;
    int c = threadIdx.x * 4;
    float* yp = y + (size_t)token * DIM + c;
    float4 acc = *reinterpret_cast<float4*>(yp);
#pragma unroll
    for (int k = 0; k < 2; ++k) {
        int s = route_slot[2 * token + k];
        if (s >= 0) {
            float gate = topk_val[2 * token + k];
            ushort4 rv = *reinterpret_cast<const ushort4*>(out_buf + (size_t)s * DIM + c);
            acc.x += gate * bf2f(rv.x); acc.y += gate * bf2f(rv.y);
            acc.z += gate * bf2f(rv.z); acc.w += gate * bf2f(rv.w);
        }
    }
    *reinterpret_cast<float4*>(yp) = acc;
}

extern "C" void kernel_launch(void* const* d_in, const int* in_sizes, int n_in,
                              void* d_out, int out_size, void* d_ws, size_t ws_size,
                              hipStream_t stream) {
    const float* x   = (const float*)d_in[0];
    const float* rw  = (const float*)d_in[1];
    const float* sgw = (const float*)d_in[2];
    const float* w1  = (const float*)d_in[3];
    const float* w2  = (const float*)d_in[4];
    const float* sw1 = (const float*)d_in[5];
    const float* sw2 = (const float*)d_in[6];
    float* y = (float*)d_out;
    float* out_tail = y + (size_t)N_TOK * DIM;

    size_t off = 0;
    char* wsb = (char*)d_ws;
    auto alloc = [&](size_t bytes) -> void* {
        void* p = wsb + off;
        off += (bytes + 255) & ~(size_t)255;
        return p;
    };
    float*    scores     = (float*)alloc((size_t)N_TOK * NEXP * 4);
    int*      topk_idx   = (int*)alloc((size_t)NROUTE * 4);
    float*    topk_val   = (float*)alloc((size_t)NROUTE * 4);
    float*    g_shared   = (float*)alloc((size_t)N_TOK * 4);
    int*      chunk_hist = (int*)alloc((size_t)NCHUNK * NEXP * 4);
    int*      chunk_off  = (int*)alloc((size_t)NCHUNK * NEXP * 4);
    int*      counts_cap = (int*)alloc((size_t)NEXP * 4);
    int*      route_slot = (int*)alloc((size_t)NROUTE * 4);
    int*      slot_token = (int*)alloc((size_t)ECAP * 4);
    ushort_t* x_bf       = (ushort_t*)alloc((size_t)N_TOK * DIM * 2);
    ushort_t* w1t        = (ushort_t*)alloc((size_t)NEXP * DIM * FDIM * 2);
    ushort_t* w2t        = (ushort_t*)alloc((size_t)NEXP * DIM * FDIM * 2);
    ushort_t* sw1t       = (ushort_t*)alloc((size_t)DIM * FDIM * 2);
    ushort_t* sw2t       = (ushort_t*)alloc((size_t)DIM * FDIM * 2);
    ushort_t* h_buf      = (ushort_t*)alloc((size_t)TOTROW * FDIM * 2);
    ushort_t* out_buf    = (ushort_t*)alloc((size_t)ECAP * DIM * 2);
    (void)ws_size; (void)in_sizes; (void)n_in; (void)out_size;

    convert_x_kernel<<<N_TOK * DIM / 2048, 256, 0, stream>>>(x, x_bf);
    transpose_w_kernel<<<4352, 256, 0, stream>>>(w1, w2, sw1, sw2, w1t, w2t, sw1t, sw2t);
    router_kernel<<<N_TOK, 64, 0, stream>>>(x, rw, sgw, scores, topk_idx, topk_val, g_shared);
    hist_kernel<<<NCHUNK, 256, 0, stream>>>(topk_idx, chunk_hist);
    scan_kernel<<<1, 64, 0, stream>>>(chunk_hist, chunk_off, counts_cap, out_tail);
    assign_kernel<<<NCHUNK, 256, 0, stream>>>(topk_idx, topk_val, chunk_off, route_slot, slot_token);
    importance_kernel<<<NEXP, 256, 0, stream>>>(scores, out_tail);

    gemm1_mfma<<<G1_NWG, 256, 0, stream>>>(x_bf, w1t, sw1t, slot_token, counts_cap, h_buf);
    gemm2_mfma<<<G2_NWG, 256, 0, stream>>>(h_buf, w2t, sw2t, counts_cap, g_shared, out_buf, y);

    combine_kernel<<<N_TOK, 256, 0, stream>>>(out_buf, route_slot, topk_val, y);
}